// Round 1
// baseline (153.994 us; speedup 1.0000x reference)
//
#include <hip/hip_runtime.h>

#define NB 32   // batch
#define NT 50   // targets per image
#define NA 3    // anchors
#define NWAVES 16

__global__ __launch_bounds__(1024) void boxloss_kernel(
    const float* __restrict__ out0, const float* __restrict__ anc0,
    const float* __restrict__ out1, const float* __restrict__ anc1,
    const float* __restrict__ out2, const float* __restrict__ anc2,
    const float* __restrict__ targets, float* __restrict__ d_out)
{
    __shared__ float s_t[NB * NT * 4];   // staged targets: [b][j][x,y,w,h] (25.6 KB)
    __shared__ float s_wsum[NWAVES];

    const int tid = threadIdx.x;

    // Stage targets[:, :, 1:5] into LDS (read once from HBM)
    for (int e = tid; e < NB * NT * 4; e += 1024) {
        int row = e >> 2;
        int c = e & 3;
        s_t[e] = targets[row * 5 + 1 + c];
    }
    __syncthreads();

    const int wave = tid >> 6;
    const int lane = tid & 63;

    float acc = 0.0f;

    // 96 (image, scale) pairs round-robin over 16 waves -> exactly 6 each
    for (int pair = wave; pair < NB * 3; pair += NWAVES) {
        const int b = pair / 3;
        const int s = pair - 3 * b;
        const int g = (s == 0) ? 52 : (s == 1 ? 26 : 13);
        const float* outp = (s == 0) ? out0 : (s == 1 ? out1 : out2);
        const float* anc  = (s == 0) ? anc0 : (s == 1 ? anc1 : anc2);
        const float gf = (float)g;

        // Per-lane target processing (lane == target index j)
        int key = 0x40000000 + lane;   // unique key: never collides with a real cell
        bool cand = false;
        float t0 = 0.f, t1 = 0.f, t2 = 0.f, t3 = 0.f;
        int cxi = 0, cyi = 0, ai = 0;

        if (lane < NT) {
            const float* tr = &s_t[(b * NT + lane) * 4];
            float r0 = tr[0], r1 = tr[1], r2 = tr[2], r3 = tr[3];
            bool valid = !(r0 == 0.f && r1 == 0.f && r2 == 0.f && r3 == 0.f);
            t0 = r0 * gf; t1 = r1 * gf; t2 = r2 * gf; t3 = r3 * gf;
            float cx = floorf(t0), cy = floorf(t1);
            // zt = [t0-cx-0.5, t1-cy-0.5, t2, t3]; rect_t = xywh2rect(zt)
            float ztx = t0 - cx - 0.5f;
            float zty = t1 - cy - 0.5f;
            float tx0 = ztx - t2 * 0.5f, ty0 = zty - t3 * 0.5f;
            float tx1 = ztx + t2 * 0.5f, ty1 = zty + t3 * 0.5f;
            // area from rect differences (matches reference bit-for-bit)
            float area_t = (tx1 - tx0) * (ty1 - ty0);
            float best = -1.f; int bi = 0;
            #pragma unroll
            for (int a = 0; a < NA; ++a) {
                float aw = anc[2 * a], ah = anc[2 * a + 1];
                float ax1 = aw * 0.5f, ay1 = ah * 0.5f;
                float ax0 = 0.f - ax1, ay0 = 0.f - ay1;
                float x0 = fmaxf(tx0, ax0), y0 = fmaxf(ty0, ay0);
                float x1 = fminf(tx1, ax1), y1 = fminf(ty1, ay1);
                float inter = (x0 < x1 && y0 < y1) ? (x1 - x0) * (y1 - y0) : 0.f;
                float area_a = (ax1 - ax0) * (ay1 - ay0);
                float uni = area_t + area_a - inter;
                float iou = inter / uni;
                if (iou > best) { best = iou; bi = a; }   // strict >: first-max wins (jnp.argmax)
            }
            bool m = (best > 0.5f) && valid;
            cxi = (int)cx; cyi = (int)cy; ai = bi;
            if (m) { key = (bi * g + cyi) * g + cxi; cand = true; }
        }

        // Scatter dedup, last-write-wins: lane j survives iff no lane j' > j has same key.
        // Non-candidates hold unique keys >= 0x40000000 (real cells < 3*52*52), so they never match.
        bool conflict = false;
        for (int j = 0; j < NT; ++j) {
            int k2 = __shfl(key, j, 64);
            if (j > lane && k2 == key) conflict = true;
        }
        bool kept = cand && !conflict &&
                    !(t0 == 0.f && t1 == 0.f && t2 == 0.f && t3 == 0.f);

        float d = 0.f;
        if (kept) {
            // gather pred[0:4] at (b, ai, cyi, cxi)
            const float* p = outp + ((((size_t)b * NA + ai) * g + cyi) * g + cxi) * 85;
            float p0 = p[0], p1 = p[1], p2 = p[2], p3 = p[3];
            float dx = p0 - t0, dy = p1 - t1;
            float rw = 1.f / sqrtf(p2) - 1.f / sqrtf(t2);
            float rh = 1.f / sqrtf(p3) - 1.f / sqrtf(t3);
            d = dx * dx + dy * dy + rw * rw + rh * rh;
        }

        unsigned long long bal = __ballot(kept);
        int n = __popcll(bal);

        // full-wave butterfly reduce of d (all 64 lanes end with the sum)
        #pragma unroll
        for (int off = 32; off >= 1; off >>= 1)
            d += __shfl_xor(d, off, 64);

        if (n > 0) acc += d / (2.0f * (float)n);
    }

    // acc is lane-uniform within each wave; cross-wave reduce via LDS
    if (lane == 0) s_wsum[wave] = acc;
    __syncthreads();
    if (tid == 0) {
        float total = 0.f;
        #pragma unroll
        for (int w = 0; w < NWAVES; ++w) total += s_wsum[w];
        d_out[0] = total / (float)NB;
    }
}

extern "C" void kernel_launch(void* const* d_in, const int* in_sizes, int n_in,
                              void* d_out, int out_size, void* d_ws, size_t ws_size,
                              hipStream_t stream) {
    const float* out0 = (const float*)d_in[0];
    const float* anc0 = (const float*)d_in[1];
    const float* out1 = (const float*)d_in[2];
    const float* anc1 = (const float*)d_in[3];
    const float* out2 = (const float*)d_in[4];
    const float* anc2 = (const float*)d_in[5];
    const float* tgts = (const float*)d_in[6];

    boxloss_kernel<<<1, 1024, 0, stream>>>(out0, anc0, out1, anc1, out2, anc2,
                                           tgts, (float*)d_out);
}

// Round 2
// 134.975 us; speedup vs baseline: 1.1409x; 1.1409x over previous
//
#include <hip/hip_runtime.h>

#define NB 32   // batch
#define NT 50   // targets per image
#define NA 3    // anchors
#define NPAIR (NB * 3)

// One block (1 wave, 64 lanes) per (image b, scale s) pair.
// Writes partial loss for this pair into ws[pair]. Deterministic, no atomics.
__global__ __launch_bounds__(64) void boxloss_pair_kernel(
    const float* __restrict__ out0, const float* __restrict__ anc0,
    const float* __restrict__ out1, const float* __restrict__ anc1,
    const float* __restrict__ out2, const float* __restrict__ anc2,
    const float* __restrict__ targets, float* __restrict__ ws)
{
    const int pair = blockIdx.x;
    const int b = pair / 3;
    const int s = pair - 3 * b;
    const int g = (s == 0) ? 52 : (s == 1 ? 26 : 13);
    const float* outp = (s == 0) ? out0 : (s == 1 ? out1 : out2);
    const float* anc  = (s == 0) ? anc0 : (s == 1 ? anc1 : anc2);
    const float gf = (float)g;
    const int lane = threadIdx.x;

    // Per-lane target processing (lane == target index j)
    int key = 0x40000000 + lane;   // unique sentinel: never collides with a real cell
    bool cand = false;
    float t0 = 0.f, t1 = 0.f, t2 = 0.f, t3 = 0.f;
    int cxi = 0, cyi = 0, ai = 0;

    if (lane < NT) {
        const float* tr = &targets[((size_t)b * NT + lane) * 5 + 1];
        float r0 = tr[0], r1 = tr[1], r2 = tr[2], r3 = tr[3];
        bool valid = !(r0 == 0.f && r1 == 0.f && r2 == 0.f && r3 == 0.f);
        t0 = r0 * gf; t1 = r1 * gf; t2 = r2 * gf; t3 = r3 * gf;
        float cx = floorf(t0), cy = floorf(t1);
        // zt = [t0-cx-0.5, t1-cy-0.5, t2, t3]; rect_t = xywh2rect(zt)
        float ztx = t0 - cx - 0.5f;
        float zty = t1 - cy - 0.5f;
        float tx0 = ztx - t2 * 0.5f, ty0 = zty - t3 * 0.5f;
        float tx1 = ztx + t2 * 0.5f, ty1 = zty + t3 * 0.5f;
        float area_t = (tx1 - tx0) * (ty1 - ty0);   // rect-difference form (matches ref)
        float best = -1.f; int bi = 0;
        #pragma unroll
        for (int a = 0; a < NA; ++a) {
            float aw = anc[2 * a], ah = anc[2 * a + 1];
            float ax1 = aw * 0.5f, ay1 = ah * 0.5f;
            float ax0 = 0.f - ax1, ay0 = 0.f - ay1;
            float x0 = fmaxf(tx0, ax0), y0 = fmaxf(ty0, ay0);
            float x1 = fminf(tx1, ax1), y1 = fminf(ty1, ay1);
            float inter = (x0 < x1 && y0 < y1) ? (x1 - x0) * (y1 - y0) : 0.f;
            float area_a = (ax1 - ax0) * (ay1 - ay0);
            float uni = area_t + area_a - inter;
            float iou = inter / uni;
            if (iou > best) { best = iou; bi = a; }   // strict >: first max wins (jnp.argmax)
        }
        bool m = (best > 0.5f) && valid;
        cxi = (int)cx; cyi = (int)cy; ai = bi;
        if (m) { key = (bi * g + cyi) * g + cxi; cand = true; }
    }

    // Scatter dedup, last-write-wins: lane j survives iff no lane j' > j maps to the
    // same cell. Non-candidates hold unique sentinels (>= 0x40000000 > 3*52*52).
    bool conflict = false;
    for (int j = 1; j < NT; ++j) {
        int k2 = __shfl(key, j, 64);
        if (j > lane && k2 == key) conflict = true;
    }
    bool kept = cand && !conflict;

    float d = 0.f;
    if (kept) {
        // gather pred[0:4] at (b, ai, cyi, cxi)
        const float* p = outp + ((((size_t)b * NA + ai) * g + cyi) * g + cxi) * 85;
        float p0 = p[0], p1 = p[1], p2 = p[2], p3 = p[3];
        float dx = p0 - t0, dy = p1 - t1;
        float rw = 1.f / sqrtf(p2) - 1.f / sqrtf(t2);
        float rh = 1.f / sqrtf(p3) - 1.f / sqrtf(t3);
        d = dx * dx + dy * dy + rw * rw + rh * rh;
    }

    unsigned long long bal = __ballot(kept);
    int n = __popcll(bal);

    // full-wave butterfly reduce of d
    #pragma unroll
    for (int off = 32; off >= 1; off >>= 1)
        d += __shfl_xor(d, off, 64);

    if (lane == 0)
        ws[pair] = (n > 0) ? d / (2.0f * (float)n) : 0.0f;
}

// Single-wave reduction of the 96 partials -> d_out[0] (divide by B).
__global__ __launch_bounds__(64) void boxloss_reduce_kernel(
    const float* __restrict__ ws, float* __restrict__ d_out)
{
    const int lane = threadIdx.x;
    float v = 0.f;
    if (lane < NPAIR) v = ws[lane];
    if (lane + 64 < NPAIR) v += ws[lane + 64];
    #pragma unroll
    for (int off = 32; off >= 1; off >>= 1)
        v += __shfl_xor(v, off, 64);
    if (lane == 0) d_out[0] = v / (float)NB;
}

extern "C" void kernel_launch(void* const* d_in, const int* in_sizes, int n_in,
                              void* d_out, int out_size, void* d_ws, size_t ws_size,
                              hipStream_t stream) {
    const float* out0 = (const float*)d_in[0];
    const float* anc0 = (const float*)d_in[1];
    const float* out1 = (const float*)d_in[2];
    const float* anc1 = (const float*)d_in[3];
    const float* out2 = (const float*)d_in[4];
    const float* anc2 = (const float*)d_in[5];
    const float* tgts = (const float*)d_in[6];
    float* ws = (float*)d_ws;

    boxloss_pair_kernel<<<NPAIR, 64, 0, stream>>>(out0, anc0, out1, anc1,
                                                  out2, anc2, tgts, ws);
    boxloss_reduce_kernel<<<1, 64, 0, stream>>>(ws, (float*)d_out);
}

// Round 3
// 133.884 us; speedup vs baseline: 1.1502x; 1.0082x over previous
//
#include <hip/hip_runtime.h>

#define NB 32   // batch
#define NT 50   // targets per image
#define NA 3    // anchors
#define NPAIR (NB * 3)

// One block (1 wave, 64 lanes) per (image b, scale s) pair.
// Writes partial loss for this pair into ws[pair]. Deterministic, no atomics.
__global__ __launch_bounds__(64) void boxloss_pair_kernel(
    const float* __restrict__ out0, const float* __restrict__ anc0,
    const float* __restrict__ out1, const float* __restrict__ anc1,
    const float* __restrict__ out2, const float* __restrict__ anc2,
    const float* __restrict__ targets, float* __restrict__ ws)
{
    const int pair = blockIdx.x;
    const int b = pair / 3;
    const int s = pair - 3 * b;
    const int g = (s == 0) ? 52 : (s == 1 ? 26 : 13);
    const float* outp = (s == 0) ? out0 : (s == 1 ? out1 : out2);
    const float* anc  = (s == 0) ? anc0 : (s == 1 ? anc1 : anc2);
    const float gf = (float)g;
    const int lane = threadIdx.x;

    // Per-lane target processing (lane == target index j)
    int key = 0x40000000 + lane;   // unique sentinel: never collides with a real cell
    bool cand = false;
    float t0 = 0.f, t1 = 0.f, t2 = 0.f, t3 = 0.f;
    float p0 = 0.f, p1 = 0.f, p2 = 1.f, p3 = 1.f;

    if (lane < NT) {
        const float* tr = &targets[((size_t)b * NT + lane) * 5 + 1];
        float r0 = tr[0], r1 = tr[1], r2 = tr[2], r3 = tr[3];
        bool valid = !(r0 == 0.f && r1 == 0.f && r2 == 0.f && r3 == 0.f);
        t0 = r0 * gf; t1 = r1 * gf; t2 = r2 * gf; t3 = r3 * gf;
        float cx = floorf(t0), cy = floorf(t1);
        // zt = [t0-cx-0.5, t1-cy-0.5, t2, t3]; rect_t = xywh2rect(zt)
        float ztx = t0 - cx - 0.5f;
        float zty = t1 - cy - 0.5f;
        float tx0 = ztx - t2 * 0.5f, ty0 = zty - t3 * 0.5f;
        float tx1 = ztx + t2 * 0.5f, ty1 = zty + t3 * 0.5f;
        float area_t = (tx1 - tx0) * (ty1 - ty0);   // rect-difference form (matches ref)
        float best = -1.f; int bi = 0;
        #pragma unroll
        for (int a = 0; a < NA; ++a) {
            float aw = anc[2 * a], ah = anc[2 * a + 1];
            float ax1 = aw * 0.5f, ay1 = ah * 0.5f;
            float ax0 = 0.f - ax1, ay0 = 0.f - ay1;
            float x0 = fmaxf(tx0, ax0), y0 = fmaxf(ty0, ay0);
            float x1 = fminf(tx1, ax1), y1 = fminf(ty1, ay1);
            float inter = (x0 < x1 && y0 < y1) ? (x1 - x0) * (y1 - y0) : 0.f;
            float area_a = (ax1 - ax0) * (ay1 - ay0);
            float uni = area_t + area_a - inter;
            float iou = inter / uni;
            if (iou > best) { best = iou; bi = a; }   // strict >: first max wins (jnp.argmax)
        }
        bool m = (best > 0.5f) && valid;
        if (m) {
            int cxi = (int)cx, cyi = (int)cy;
            key = (bi * g + cyi) * g + cxi;
            cand = true;
            // HOISTED gather: address known pre-dedup; issue now so the ~900-cycle
            // HBM latency overlaps the 49-step shfl scan below. Values used only if kept.
            const float* p = outp + ((((size_t)b * NA + bi) * g + cyi) * g + cxi) * 85;
            p0 = p[0]; p1 = p[1]; p2 = p[2]; p3 = p[3];
        }
    }

    // Scatter dedup, last-write-wins: lane j survives iff no lane j' > j maps to the
    // same cell. Non-candidates hold unique sentinels (>= 0x40000000 > 3*52*52).
    bool conflict = false;
    for (int j = 1; j < NT; ++j) {
        int k2 = __shfl(key, j, 64);
        if (j > lane && k2 == key) conflict = true;
    }
    bool kept = cand && !conflict;

    float d = 0.f;
    if (kept) {
        float dx = p0 - t0, dy = p1 - t1;
        float rw = 1.f / sqrtf(p2) - 1.f / sqrtf(t2);
        float rh = 1.f / sqrtf(p3) - 1.f / sqrtf(t3);
        d = dx * dx + dy * dy + rw * rw + rh * rh;
    }

    unsigned long long bal = __ballot(kept);
    int n = __popcll(bal);

    // full-wave butterfly reduce of d
    #pragma unroll
    for (int off = 32; off >= 1; off >>= 1)
        d += __shfl_xor(d, off, 64);

    if (lane == 0)
        ws[pair] = (n > 0) ? d / (2.0f * (float)n) : 0.0f;
}

// Single-wave reduction of the 96 partials -> d_out[0] (divide by B).
__global__ __launch_bounds__(64) void boxloss_reduce_kernel(
    const float* __restrict__ ws, float* __restrict__ d_out)
{
    const int lane = threadIdx.x;
    float v = 0.f;
    if (lane < NPAIR) v = ws[lane];
    if (lane + 64 < NPAIR) v += ws[lane + 64];
    #pragma unroll
    for (int off = 32; off >= 1; off >>= 1)
        v += __shfl_xor(v, off, 64);
    if (lane == 0) d_out[0] = v / (float)NB;
}

extern "C" void kernel_launch(void* const* d_in, const int* in_sizes, int n_in,
                              void* d_out, int out_size, void* d_ws, size_t ws_size,
                              hipStream_t stream) {
    const float* out0 = (const float*)d_in[0];
    const float* anc0 = (const float*)d_in[1];
    const float* out1 = (const float*)d_in[2];
    const float* anc1 = (const float*)d_in[3];
    const float* out2 = (const float*)d_in[4];
    const float* anc2 = (const float*)d_in[5];
    const float* tgts = (const float*)d_in[6];
    float* ws = (float*)d_ws;

    boxloss_pair_kernel<<<NPAIR, 64, 0, stream>>>(out0, anc0, out1, anc1,
                                                  out2, anc2, tgts, ws);
    boxloss_reduce_kernel<<<1, 64, 0, stream>>>(ws, (float*)d_out);
}